// Round 6
// baseline (241.147 us; speedup 1.0000x reference)
//
#include <hip/hip_runtime.h>
#include <math.h>

#define EPS 1e-6f
#define C_CH 64          // channels (fixed by reference)
#define NAPPLY 1024      // apply blocks per phase

typedef float f32x4 __attribute__((ext_vector_type(4)));

// ---------------------------------------------------------------------------
// One phase kernel, three roles by block index:
//   [0, nA)        : apply   segment p-2   (reads mul[p-2], nt-stores out)
//   [nA, nA+nS)    : sumsq   segment p     (writes partial[p][bip][64])
//   [nA+nS]        : finalize segment p-1  (partial -> mul, one block)
// Phase p's kernel boundary provides the S(i) -> F(i) -> A(i) ordering.
// 32 MB phase granularity keeps the apply re-read L3-resident (depth-2 lag).
// ---------------------------------------------------------------------------
__global__ __launch_bounds__(256) void k_phase(
    const float4* __restrict__ feat,
    const int*    __restrict__ offset,
    float*        __restrict__ partial,   // [B][R][64]
    float*        __restrict__ muls,      // [B][64]
    const float*  __restrict__ gamma,     // [64]
    const float4* __restrict__ beta4,     // [16]
    f32x4*        __restrict__ out,
    int p, int nA, int nS, int R)
{
    __shared__ float lds[16][C_CH];

    const int t    = threadIdx.x;
    const int c4   = t & 15;
    const int rsub = t >> 4;
    const int bid  = blockIdx.x;

    if (bid < nA) {
        // ----------------- APPLY role: segment p-2 -----------------
        const int seg   = p - 2;
        const int start = (seg == 0) ? 0 : offset[seg - 1];
        const int end   = offset[seg];

        const float4 mm = ((const float4*)(muls + seg * C_CH))[c4];
        const float4 bt = beta4[c4];

        const int stride = nA * 32;
        for (int row = start + bid * 32 + rsub; row < end; row += stride) {
            float4 v = feat[row * 16 + c4];
            f32x4 o;
            o.x = fmaf(v.x, mm.x, bt.x);
            o.y = fmaf(v.y, mm.y, bt.y);
            o.z = fmaf(v.z, mm.z, bt.z);
            o.w = fmaf(v.w, mm.w, bt.w);
            __builtin_nontemporal_store(o, &out[row * 16 + c4]);
            int row2 = row + 16;
            if (row2 < end) {
                float4 w = feat[row2 * 16 + c4];
                f32x4 o2;
                o2.x = fmaf(w.x, mm.x, bt.x);
                o2.y = fmaf(w.y, mm.y, bt.y);
                o2.z = fmaf(w.z, mm.z, bt.z);
                o2.w = fmaf(w.w, mm.w, bt.w);
                __builtin_nontemporal_store(o2, &out[row2 * 16 + c4]);
            }
        }
    } else if (bid < nA + nS) {
        // ----------------- SUMSQ role: segment p -----------------
        const int seg   = p;
        const int bip   = bid - nA;
        const int start = (seg == 0) ? 0 : offset[seg - 1];
        const int end   = offset[seg];

        float4 a0 = make_float4(0.f, 0.f, 0.f, 0.f);
        float4 a1 = make_float4(0.f, 0.f, 0.f, 0.f);

        const int stride = R * 32;
        for (int row = start + bip * 32 + rsub; row < end; row += stride) {
            float4 v = feat[row * 16 + c4];
            a0.x = fmaf(v.x, v.x, a0.x);
            a0.y = fmaf(v.y, v.y, a0.y);
            a0.z = fmaf(v.z, v.z, a0.z);
            a0.w = fmaf(v.w, v.w, a0.w);
            int row2 = row + 16;
            if (row2 < end) {
                float4 w = feat[row2 * 16 + c4];
                a1.x = fmaf(w.x, w.x, a1.x);
                a1.y = fmaf(w.y, w.y, a1.y);
                a1.z = fmaf(w.z, w.z, a1.z);
                a1.w = fmaf(w.w, w.w, a1.w);
            }
        }
        a0.x += a1.x; a0.y += a1.y; a0.z += a1.z; a0.w += a1.w;

        lds[rsub][4 * c4 + 0] = a0.x;
        lds[rsub][4 * c4 + 1] = a0.y;
        lds[rsub][4 * c4 + 2] = a0.z;
        lds[rsub][4 * c4 + 3] = a0.w;
        __syncthreads();

        if (t < C_CH) {
            float s = 0.f;
            #pragma unroll
            for (int r = 0; r < 16; ++r) s += lds[r][t];
            partial[(seg * R + bip) * C_CH + t] = s;
        }
    } else {
        // ----------------- FINALIZE role: segment p-1 (one block) -----------------
        const int seg = p - 1;
        const float* base = partial + seg * R * C_CH;

        float4 acc = make_float4(0.f, 0.f, 0.f, 0.f);
        for (int r = rsub; r < R; r += 16) {
            float4 v = ((const float4*)(base + r * C_CH))[c4];
            acc.x += v.x; acc.y += v.y; acc.z += v.z; acc.w += v.w;
        }
        lds[rsub][4 * c4 + 0] = acc.x;
        lds[rsub][4 * c4 + 1] = acc.y;
        lds[rsub][4 * c4 + 2] = acc.z;
        lds[rsub][4 * c4 + 3] = acc.w;
        __syncthreads();

        if (t < C_CH) {
            float s = 0.f;
            #pragma unroll
            for (int r = 0; r < 16; ++r) s += lds[r][t];
            float resp = sqrtf(s);
            float m = resp;
            #pragma unroll
            for (int off = 1; off < 64; off <<= 1) m += __shfl_xor(m, off, 64);
            float mean = m * (1.0f / 64.0f);
            muls[seg * C_CH + t] = 1.0f + gamma[t] * (resp / (mean + EPS));
        }
    }
}

// ---------------------------------------------------------------------------
extern "C" void kernel_launch(void* const* d_in, const int* in_sizes, int n_in,
                              void* d_out, int out_size, void* d_ws, size_t ws_size,
                              hipStream_t stream)
{
    const float4* feat   = (const float4*)d_in[0];
    const int*    offset = (const int*)d_in[1];
    const float*  gamma  = (const float*)d_in[2];
    const float4* beta4  = (const float4*)d_in[3];
    f32x4*        out    = (f32x4*)d_out;

    const int B = in_sizes[1];   // number of segments (8)

    // sumsq blocks per segment; clamp so partial + muls fit the workspace
    int R = 1024;
    while ((size_t)B * R * C_CH * 4 + (size_t)B * C_CH * 4 > ws_size && R > 64)
        R >>= 1;

    float* partial = (float*)d_ws;                 // [B][R][64]
    float* muls    = partial + (size_t)B * R * C_CH;  // [B][64]

    // Pipeline: phase p runs  A(p-2) | S(p) | F(p-1)
    for (int p = 0; p <= B + 1; ++p) {
        const int nA   = (p >= 2) ? NAPPLY : 0;
        const int nS   = (p < B) ? R : 0;
        const int hasF = (p >= 1 && p <= B) ? 1 : 0;
        const int grid = nA + nS + hasF;
        if (grid == 0) continue;
        k_phase<<<grid, 256, 0, stream>>>(feat, offset, partial, muls,
                                          gamma, beta4, out, p, nA, nS, R);
    }
}